// Round 17
// baseline (140.824 us; speedup 1.0000x reference)
//
#include <hip/hip_runtime.h>
#include <hip/hip_cooperative_groups.h>

namespace cg = cooperative_groups;

#define GB 64
#define GN 128
#define F_OBS 64
#define F_TOT 80
#define NBLK 1024           // 64 batches x 16 block-pairs
#define NT 256              // 4 waves; g = tid>>7 picks the row-quad
#define IPT 4               // rows per thread

// R17: single cooperative node. R13-R16 isolated the residual as the
// two-node graph tax (~10us documented launch floor + dependent reduce
// node); every in-kernel lever is exhausted (R10/R12/R15/R16 all neutral).
// grid.sync() (ONE two-phase barrier; the sanctioned cooperative path) lets
// block 0 finish probs in the same node -- NOT R2's per-block fence storm.
// Body identical to R16: XCD-clustered batches (R14), own-row prefetch
// (R10), rows on the scalar pipe (R7), per-wave part stores (R16),
// product-of-factors loglik (R16).
__global__ __launch_bounds__(NT, 4) void glcn_coop(
    const float* __restrict__ h, const float* __restrict__ w,
    float* __restrict__ Aout, float* __restrict__ probs,
    float* __restrict__ part) {
  const int blk = blockIdx.x;
  const int b   = (blk & 7) + 8 * ((blk >> 3) & 7);  // batch: XCD-clustered
  const int qq  = blk >> 6;                          // 0..15 block-pair index
  const int tid = threadIdx.x;
  const int j   = tid & (GN - 1);
  const int g   = __builtin_amdgcn_readfirstlane(tid >> 7);  // 0..1
  const int is  = qq * 8 + g * IPT;                  // wave-uniform row base

  const float* rowj = h + ((size_t)(b * GN + j)) * F_TOT;    // per-lane
  const float* rows = h + ((size_t)(b * GN + is)) * F_TOT;   // uniform->s_load

  // Own row prefetched once: 16 independent float4 loads, one drain.
  float4 hj[F_OBS / 4];
#pragma unroll
  for (int kq = 0; kq < F_OBS / 4; ++kq)
    hj[kq] = *reinterpret_cast<const float4*>(rowj + 4 * kq);

  float acc[IPT];
#pragma unroll
  for (int ii = 0; ii < IPT; ++ii) acc[ii] = 0.f;

#pragma unroll
  for (int kq = 0; kq < F_OBS / 4; ++kq) {
    const float4 hv = hj[kq];
    const float4 wv = *reinterpret_cast<const float4*>(w + 4 * kq);  // scalar
#pragma unroll
    for (int ii = 0; ii < IPT; ++ii) {
      const float* ri = rows + ii * F_TOT + 4 * kq;   // scalar dwordx4
      acc[ii] = fmaf(wv.x, fabsf(hv.x - ri[0]), acc[ii]);
      acc[ii] = fmaf(wv.y, fabsf(hv.y - ri[1]), acc[ii]);
      acc[ii] = fmaf(wv.z, fabsf(hv.z - ri[2]), acc[ii]);
      acc[ii] = fmaf(wv.w, fabsf(hv.w - ri[3]), acc[ii]);
    }
  }

  // Epilogue. A[i][j] = (x>0)|(i==j); selected = sigmoid(|x|);
  // per-thread loglik = -log( prod_i (i==j ? 1 : 1+exp(-|x_i|)) ).
  float prod = 1.f;
  float* Abase = Aout + (size_t)b * GN * GN;
#pragma unroll
  for (int ii = 0; ii < IPT; ++ii) {
    const int i = is + ii;
    const float x = acc[ii];
    const float f = 1.f + __expf(-fabsf(x));
    float Aval = (x > 0.f) ? 1.f : 0.f;
    if (i == j) Aval = 1.f;      // diagonal: forced 1, excluded from loglik
    else        prod *= f;
    Abase[(size_t)i * GN + j] = Aval;   // lanes = consecutive j: coalesced
  }
  float lsum = -__logf(prod);

  // Per-wave reduction: shfl tree, lane 0 stores. No LDS, no block barrier.
#pragma unroll
  for (int off = 32; off > 0; off >>= 1)
    lsum += __shfl_down(lsum, off, 64);
  const int wid = tid >> 6;                     // 0..3
  if ((tid & 63) == 0) {
    const int slice = qq * 4 + wid;             // 0..63, unique per (blk,wave)
    part[(size_t)slice * GB + b] = lsum;        // [64][GB]: coalesced reduce
  }

  // ONE grid-wide barrier, then block 0 finishes probs (fixed order sum).
  cg::this_grid().sync();
  if (blk == 0 && tid < GB) {
    float s = 0.f;
#pragma unroll
    for (int q = 0; q < 64; ++q) s += part[(size_t)q * GB + tid];
    probs[tid] = s;
  }
}

extern "C" void kernel_launch(void* const* d_in, const int* in_sizes, int n_in,
                              void* d_out, int out_size, void* d_ws, size_t ws_size,
                              hipStream_t stream) {
  const float* h = (const float*)d_in[0];   // [64,128,80] f32
  const float* w = (const float*)d_in[1];   // [64,1] f32
  float* Aout  = (float*)d_out;                       // [64,128,128]
  float* probs = Aout + (size_t)GB * GN * GN;         // [64]
  float* part  = (float*)d_ws;                        // 64*GB floats (16KB)

  void* args[] = {(void*)&h, (void*)&w, (void*)&Aout, (void*)&probs,
                  (void*)&part};
  hipLaunchCooperativeKernel((void*)glcn_coop, dim3(NBLK), dim3(NT),
                             args, 0, stream);
}

// Round 18
// 14.246 us; speedup vs baseline: 9.8853x; 9.8853x over previous
//
#include <hip/hip_runtime.h>

#define GB 64
#define GN 128
#define F_OBS 64
#define F_TOT 80
#define NBLK 1024           // 64 batches x 16 block-pairs
#define NT 256              // 4 waves; g = tid>>7 picks the row-quad
#define IPT 4               // rows per thread

// R18 = R16 restored (best measured: 14.34us). R17's cooperative single-node
// cost 140us (grid.sync ~110us across 8 non-coherent XCD L2s) -- third and
// final confirmation that ANY device-scope rendezvous dwarfs this workload.
//
// Final structure and why:
//  * Two plain dispatches (main + 64-thr reduce): beats every merged variant
//    (R5 atomics+memset 30us, R7 gather-probs 46us, R11 hetero 28us, R17
//    coop 141us). The ~10us 2-node launch/replay floor is the dominant cost
//    and is not reachable from kernel code.
//  * 1024 x 256thr, 4 waves/SIMD (R8/R9 sweep: 2->4 waves -2.9us, 8 waves
//    regressed on per-thread fixed costs).
//  * XCD-clustered batches b=(blk&7)+8*((blk>>3)&7): each XCD touches 8
//    batches = 320KB of h -> L2-resident (R13 FETCH showed 8x2.6MB HBM
//    re-stream without it; -1.4us with).
//  * Rows + w stream on the scalar pipe (wave-uniform addresses); own row
//    per-lane, prefetched once. Per-lane partner gathers are 8x HBM (R7).
//  * Epilogue: A = (x>0)|(i==j); selected = sigmoid(|x|);
//    loglik = -log(prod(1+e^-|x|)) -- one v_log per thread.
//  * part[] per-wave (no LDS, no barrier), [64][GB] layout -> reduce kernel
//    does 64 fully-coalesced loads, fixed order -> deterministic replay.
__global__ __launch_bounds__(NT, 4) void glcn_main(
    const float* __restrict__ h, const float* __restrict__ w,
    float* __restrict__ Aout, float* __restrict__ part) {
  const int blk = blockIdx.x;
  const int b   = (blk & 7) + 8 * ((blk >> 3) & 7);  // batch: XCD-clustered
  const int qq  = blk >> 6;                          // 0..15 block-pair index
  const int tid = threadIdx.x;
  const int j   = tid & (GN - 1);
  const int g   = __builtin_amdgcn_readfirstlane(tid >> 7);  // 0..1
  const int is  = qq * 8 + g * IPT;                  // wave-uniform row base

  const float* rowj = h + ((size_t)(b * GN + j)) * F_TOT;    // per-lane
  const float* rows = h + ((size_t)(b * GN + is)) * F_TOT;   // uniform->s_load

  // Own row prefetched once: 16 independent float4 loads, one drain.
  float4 hj[F_OBS / 4];
#pragma unroll
  for (int kq = 0; kq < F_OBS / 4; ++kq)
    hj[kq] = *reinterpret_cast<const float4*>(rowj + 4 * kq);

  float acc[IPT];
#pragma unroll
  for (int ii = 0; ii < IPT; ++ii) acc[ii] = 0.f;

#pragma unroll
  for (int kq = 0; kq < F_OBS / 4; ++kq) {
    const float4 hv = hj[kq];
    const float4 wv = *reinterpret_cast<const float4*>(w + 4 * kq);  // scalar
#pragma unroll
    for (int ii = 0; ii < IPT; ++ii) {
      const float* ri = rows + ii * F_TOT + 4 * kq;   // scalar dwordx4
      acc[ii] = fmaf(wv.x, fabsf(hv.x - ri[0]), acc[ii]);
      acc[ii] = fmaf(wv.y, fabsf(hv.y - ri[1]), acc[ii]);
      acc[ii] = fmaf(wv.z, fabsf(hv.z - ri[2]), acc[ii]);
      acc[ii] = fmaf(wv.w, fabsf(hv.w - ri[3]), acc[ii]);
    }
  }

  // Epilogue. A[i][j] = (x>0)|(i==j); selected = sigmoid(|x|);
  // per-thread loglik = -log( prod_i (i==j ? 1 : 1+exp(-|x_i|)) ).
  float prod = 1.f;
  float* Abase = Aout + (size_t)b * GN * GN;
#pragma unroll
  for (int ii = 0; ii < IPT; ++ii) {
    const int i = is + ii;
    const float x = acc[ii];
    const float f = 1.f + __expf(-fabsf(x));
    float Aval = (x > 0.f) ? 1.f : 0.f;
    if (i == j) Aval = 1.f;      // diagonal: forced 1, excluded from loglik
    else        prod *= f;
    Abase[(size_t)i * GN + j] = Aval;   // lanes = consecutive j: coalesced
  }
  float lsum = -__logf(prod);

  // Per-WAVE reduction only: shfl tree, lane 0 stores. No LDS, no barrier.
#pragma unroll
  for (int off = 32; off > 0; off >>= 1)
    lsum += __shfl_down(lsum, off, 64);
  const int wid = tid >> 6;                     // 0..3
  if ((tid & 63) == 0) {
    const int slice = qq * 4 + wid;             // 0..63, unique per (blk,wave)
    part[(size_t)slice * GB + b] = lsum;        // [64][GB]: coalesced reduce
  }
}

// probs[b] = sum of the 64 wave partials, fixed slice order (deterministic);
// every load is fully coalesced across the 64 threads.
__global__ __launch_bounds__(64) void glcn_reduce(
    const float* __restrict__ part, float* __restrict__ probs) {
  const int b = threadIdx.x;
  float s = 0.f;
#pragma unroll
  for (int q = 0; q < 64; ++q) s += part[(size_t)q * GB + b];
  probs[b] = s;
}

extern "C" void kernel_launch(void* const* d_in, const int* in_sizes, int n_in,
                              void* d_out, int out_size, void* d_ws, size_t ws_size,
                              hipStream_t stream) {
  const float* h = (const float*)d_in[0];   // [64,128,80] f32
  const float* w = (const float*)d_in[1];   // [64,1] f32
  float* Aout  = (float*)d_out;                       // [64,128,128]
  float* probs = Aout + (size_t)GB * GN * GN;         // [64]
  float* part  = (float*)d_ws;                        // 64*GB floats (16KB)

  glcn_main<<<NBLK, NT, 0, stream>>>(h, w, Aout, part);
  glcn_reduce<<<1, 64, 0, stream>>>(part, probs);
}